// Round 10
// baseline (1017.833 us; speedup 1.0000x reference)
//
#include <hip/hip_runtime.h>

// Steerable pyramid, depthwise convs, NHWC fp32, C=16 (= 4 x float4).
// Branch-free convs over zero-padded workspace buffers.
// KEY CHANGE (r10): vertical register reuse. Each thread computes a
// 2px x 2row micro-tile; the 10 input rows are loaded ONCE each and feed
// both output rows from registers -> loads/px drop 1.8x (the load pipe,
// not VALU, was the binding resource). Fully unrolled i-loop (static
// acc/v indexing), bounded accumulators (~120 VGPR, 3 waves/SIMD).
// XCD-aware: n = blockIdx & 7. nt stores for d_out, cached for ws.

static __device__ __forceinline__ float4 f4z() { return make_float4(0.f, 0.f, 0.f, 0.f); }

static __device__ __forceinline__ float4 fmaf4(float f, float4 v, float4 a) {
    a.x = fmaf(f, v.x, a.x);
    a.y = fmaf(f, v.y, a.y);
    a.z = fmaf(f, v.z, a.z);
    a.w = fmaf(f, v.w, a.w);
    return a;
}

typedef __attribute__((ext_vector_type(4))) float f32x4;

static __device__ __forceinline__ void nt_store(float4* p, float4 v) {
    __builtin_nontemporal_store(*(const f32x4*)&v, (f32x4*)p);
}

// ---------------------------------------------------------------- pad helpers

__global__ __launch_bounds__(256) void pad_copy_img(
    const float4* __restrict__ src, float4* __restrict__ dst)
{
    const int W = 256, P = 4, Wp = 264;
    int n = blockIdx.x & 7;
    int q = blockIdx.x >> 3;                 // 1089 per n
    int e = q * 256 + threadIdx.x;
    int c4 = e & 3;
    int pix = e >> 2;
    int yp = pix / Wp;
    int xp = pix - yp * Wp;
    int y = yp - P, x = xp - P;
    bool ok = ((unsigned)y < (unsigned)W) && ((unsigned)x < (unsigned)W);
    int yc = min(max(y, 0), W - 1), xc = min(max(x, 0), W - 1);
    float4 v = src[(((n * W + yc) * W + xc) << 2) + c4];
    if (!ok) v = f4z();
    dst[((size_t)n * Wp * Wp + pix) * 4 + c4] = v;
}

__global__ __launch_bounds__(256) void zero_pads_all(
    float4* __restrict__ L0, float4* __restrict__ L1,
    float4* __restrict__ L2, float4* __restrict__ L3)
{
    int b = blockIdx.x;
    float4* buf; int W;
    if (b < 1056)      { buf = L0; W = 256; }
    else if (b < 1600) { buf = L1; W = 128; b -= 1056; }
    else if (b < 1888) { buf = L2; W = 64;  b -= 1600; }
    else               { buf = L3; W = 32;  b -= 1888; }
    int Wp = W + 16;
    int perN = 16 * Wp + 16 * W;
    int tid = b * 256 + threadIdx.x;
    int c4 = tid & 3;
    int p  = tid >> 2;
    int n  = p / perN;
    int r  = p - n * perN;
    int y, x;
    if (r < 16 * Wp) {
        int row = r / Wp;
        x = r - row * Wp;
        y = (row < 8) ? row : (W + row);
    } else {
        int q = r - 16 * Wp;
        y = 8 + (q >> 4);
        int xi = q & 15;
        x = (xi < 8) ? xi : (Wp - 16 + xi);
    }
    buf[((size_t)(n * Wp + y) * Wp + x) * 4 + c4] = f4z();
}

// ---------------------------------------------------------------- convs

// hi0 + lo0 from padded image (pad 4, Wp=264). 4px x 2row per thread.
// 256 thr = 4 c4 x 16 xg x 4 ysl. Tile = 64px x 8 rows. grid 8*4xt*32yt.
__global__ __launch_bounds__(256, 3) void dual_rows(
    const float4* __restrict__ in,   // 264 wide, pad 4
    float4* __restrict__ hi0,        // flat 256 (d_out, nt)
    float4* __restrict__ lo0,        // 272 wide, pad 8 (ws, cached)
    const float* __restrict__ fh, const float* __restrict__ fl)
{
    const int Wp = 264;
    int n = blockIdx.x & 7;
    int q = blockIdx.x >> 3;
    int xt = q & 3, yt = q >> 2;
    int t = threadIdx.x;
    int c4 = t & 3;
    int xg = (t >> 2) & 15;
    int ysl = t >> 6;
    int x0 = xt * 64 + xg * 4;
    int y0 = yt * 8 + ysl * 2;

    const float4* rp = in + ((size_t)(n * Wp + y0) * Wp + x0) * 4 + c4;
    const size_t rstep = (size_t)Wp * 4;

    float4 acc[2][4][2];                 // [row][px][hi/lo]
    #pragma unroll
    for (int r = 0; r < 2; ++r)
        #pragma unroll
        for (int p = 0; p < 4; ++p) { acc[r][p][0] = f4z(); acc[r][p][1] = f4z(); }

    #pragma unroll
    for (int i = 0; i < 10; ++i) {
        float4 v[12];
        #pragma unroll
        for (int j = 0; j < 12; ++j) v[j] = rp[j * 4];
        rp += rstep;
        #pragma unroll
        for (int r = 0; r < 2; ++r) {
            const int dy = i - r;
            if (dy >= 0 && dy < 9) {
                const float* wh = fh + dy * 9;
                const float* wl = fl + dy * 9;
                #pragma unroll
                for (int dx = 0; dx < 9; ++dx) {
                    float h = wh[dx], l = wl[dx];
                    #pragma unroll
                    for (int p = 0; p < 4; ++p) {
                        acc[r][p][0] = fmaf4(h, v[p + dx], acc[r][p][0]);
                        acc[r][p][1] = fmaf4(l, v[p + dx], acc[r][p][1]);
                    }
                }
            }
        }
    }

    #pragma unroll
    for (int r = 0; r < 2; ++r) {
        size_t hidx = ((size_t)(n * 256 + y0 + r) * 256 + x0) * 4 + c4;
        size_t lidx = ((size_t)(n * 272 + y0 + r + 8) * 272 + x0 + 8) * 4 + c4;
        #pragma unroll
        for (int p = 0; p < 4; ++p) {
            nt_store(&hi0[hidx + p * 4], acc[r][p][0]);
            lo0[lidx + p * 4] = acc[r][p][1];
        }
    }
}

// 4 band convs, 2px x 2row per thread, from padded (pad 8) lo buffer.
// 256 thr = 4 c4 x 32 xg x 2 ysl. Tile = 64px x 4 rows.
// grid = 8 * (W/64 xt) * (W/4 yt).
template <int LOGW>
__global__ __launch_bounds__(256, 3) void bands_rows(
    const float4* __restrict__ in,
    float4* __restrict__ b0, float4* __restrict__ b1,
    float4* __restrict__ b2, float4* __restrict__ b3,
    const float* __restrict__ bf)    // 4*81 contiguous
{
    const int W = 1 << LOGW, Wp = W + 16;
    const int XT = W / 64;
    int n = blockIdx.x & 7;
    int q = blockIdx.x >> 3;
    int xt = q & (XT - 1);
    int yt = q >> (LOGW - 6);
    int t = threadIdx.x;
    int c4 = t & 3;
    int xg = (t >> 2) & 31;
    int ysl = t >> 7;
    int x0 = xt * 64 + xg * 2;
    int y0 = yt * 4 + ysl * 2;

    const float4* rp = in + ((size_t)(n * Wp + y0 + 4) * Wp + (x0 + 4)) * 4 + c4;
    const size_t rstep = (size_t)Wp * 4;

    float4 acc[2][2][4];                 // [row][px][filter]
    #pragma unroll
    for (int r = 0; r < 2; ++r)
        #pragma unroll
        for (int p = 0; p < 2; ++p)
            #pragma unroll
            for (int f = 0; f < 4; ++f) acc[r][p][f] = f4z();

    #pragma unroll
    for (int i = 0; i < 10; ++i) {
        float4 v[10];
        #pragma unroll
        for (int j = 0; j < 10; ++j) v[j] = rp[j * 4];
        rp += rstep;
        #pragma unroll
        for (int r = 0; r < 2; ++r) {
            const int dy = i - r;
            if (dy >= 0 && dy < 9) {
                const float* wr = bf + dy * 9;
                #pragma unroll
                for (int dx = 0; dx < 9; ++dx) {
                    float w0 = wr[dx], w1 = wr[81 + dx];
                    float w2 = wr[162 + dx], w3 = wr[243 + dx];
                    #pragma unroll
                    for (int p = 0; p < 2; ++p) {
                        acc[r][p][0] = fmaf4(w0, v[p + dx], acc[r][p][0]);
                        acc[r][p][1] = fmaf4(w1, v[p + dx], acc[r][p][1]);
                        acc[r][p][2] = fmaf4(w2, v[p + dx], acc[r][p][2]);
                        acc[r][p][3] = fmaf4(w3, v[p + dx], acc[r][p][3]);
                    }
                }
            }
        }
    }

    #pragma unroll
    for (int r = 0; r < 2; ++r) {
        size_t idx = ((size_t)(n * W + y0 + r) * W + x0) * 4 + c4;
        #pragma unroll
        for (int p = 0; p < 2; ++p) {
            nt_store(&b0[idx + p * 4], acc[r][p][0]);
            nt_store(&b1[idx + p * 4], acc[r][p][1]);
            nt_store(&b2[idx + p * 4], acc[r][p][2]);
            nt_store(&b3[idx + p * 4], acc[r][p][3]);
        }
    }
}

// 17x17 stride-2 downsample, L{s} (pad 8) -> L{s+1} (pad 8, cached).
// 2px/thread. LOGW = input log2 width (8 or 7).
template <int LOGW>
__global__ __launch_bounds__(256, 4) void down17(
    const float4* __restrict__ in, float4* __restrict__ lo_out,
    const float* __restrict__ lf)
{
    const int W = 1 << LOGW, Wo = W >> 1, Wp = W + 16;
    int n = blockIdx.x & 7;
    int q = blockIdx.x >> 3;
    int t = threadIdx.x;
    int c4 = t & 3;
    int xg = (t >> 2) & (Wo / 2 - 1);
    int ry = t >> LOGW;                      // rows_pb = 2^(8-LOGW)
    int yo = q * (1 << (8 - LOGW)) + ry;
    int xo0 = xg * 2;
    const float4* rp = in + ((size_t)(n * Wp + 2 * yo) * Wp + 2 * xo0) * 4 + c4;
    const size_t rstep = (size_t)Wp * 4;

    float4 ac0 = f4z(), ac1 = f4z();
    #pragma unroll 1
    for (int dy = 0; dy < 17; ++dy) {
        float4 v[19];
        #pragma unroll
        for (int j = 0; j < 19; ++j) v[j] = rp[j * 4];
        rp += rstep;
        const float* wp = lf + dy * 17;
        #pragma unroll
        for (int dx = 0; dx < 17; ++dx) {
            float w = wp[dx];
            ac0 = fmaf4(w, v[dx], ac0);
            ac1 = fmaf4(w, v[dx + 2], ac1);
        }
    }
    const int W1 = Wo + 16;
    size_t oidx = ((size_t)(n * W1 + yo + 8) * W1 + xo0 + 8) * 4 + c4;
    lo_out[oidx] = ac0;
    lo_out[oidx + 4] = ac1;
}

// ------------------------------------- scales 2..3 fused (round-9 structure)

template <int LOGW>
__global__ __launch_bounds__(256, 4) void scale_fused2(
    const float4* __restrict__ in,
    float4* __restrict__ b0, float4* __restrict__ b1,
    float4* __restrict__ b2, float4* __restrict__ b3,
    float4* __restrict__ lo_out,
    const float* __restrict__ bf, const float* __restrict__ lf,
    int outPad)
{
    const int W = 1 << LOGW, Wp = W + 16;
    const int bandsPerN = (W * W) >> 7;
    int n = blockIdx.x & 7;
    int q = blockIdx.x >> 3;
    int t = threadIdx.x;
    int c4 = t & 3;

    if (q < bandsPerN) {
        int xg2 = (t >> 2) & (W / 2 - 1);
        int ry = t >> (LOGW + 1);
        int y = q * (1 << (7 - LOGW)) + ry;
        int x0 = xg2 * 2;
        const float4* rp = in + ((size_t)(n * Wp + y + 4) * Wp + (x0 + 4)) * 4 + c4;
        const size_t rstep = (size_t)Wp * 4;

        float4 a00 = f4z(), a01 = f4z(), a02 = f4z(), a03 = f4z();
        float4 a10 = f4z(), a11 = f4z(), a12 = f4z(), a13 = f4z();
        #pragma unroll 1
        for (int dy = 0; dy < 9; ++dy) {
            float4 v[10];
            #pragma unroll
            for (int j = 0; j < 10; ++j) v[j] = rp[j * 4];
            rp += rstep;
            const float* wr = bf + dy * 9;
            #pragma unroll
            for (int dx = 0; dx < 9; ++dx) {
                float w0 = wr[dx], w1 = wr[81 + dx], w2 = wr[162 + dx], w3 = wr[243 + dx];
                a00 = fmaf4(w0, v[dx], a00);
                a01 = fmaf4(w1, v[dx], a01);
                a02 = fmaf4(w2, v[dx], a02);
                a03 = fmaf4(w3, v[dx], a03);
                a10 = fmaf4(w0, v[dx + 1], a10);
                a11 = fmaf4(w1, v[dx + 1], a11);
                a12 = fmaf4(w2, v[dx + 1], a12);
                a13 = fmaf4(w3, v[dx + 1], a13);
            }
        }
        size_t idx = ((size_t)(n * W + y) * W + x0) * 4 + c4;
        nt_store(&b0[idx], a00); nt_store(&b0[idx + 4], a10);
        nt_store(&b1[idx], a01); nt_store(&b1[idx + 4], a11);
        nt_store(&b2[idx], a02); nt_store(&b2[idx + 4], a12);
        nt_store(&b3[idx], a03); nt_store(&b3[idx + 4], a13);
    } else {
        const int Wo = W >> 1;
        int q2 = q - bandsPerN;
        int xg2 = (t >> 2) & (Wo / 2 - 1);
        int ry = t >> LOGW;
        int yo = q2 * (1 << (8 - LOGW)) + ry;
        int xo0 = xg2 * 2;
        const float4* rp = in + ((size_t)(n * Wp + 2 * yo) * Wp + 2 * xo0) * 4 + c4;
        const size_t rstep = (size_t)Wp * 4;

        float4 ac0 = f4z(), ac1 = f4z();
        #pragma unroll 1
        for (int dy = 0; dy < 17; ++dy) {
            float4 v[19];
            #pragma unroll
            for (int j = 0; j < 19; ++j) v[j] = rp[j * 4];
            rp += rstep;
            const float* wp = lf + dy * 17;
            #pragma unroll
            for (int dx = 0; dx < 17; ++dx) {
                float w = wp[dx];
                ac0 = fmaf4(w, v[dx], ac0);
                ac1 = fmaf4(w, v[dx + 2], ac1);
            }
        }
        int W1 = Wo + 2 * outPad;
        size_t oidx = ((size_t)(n * W1 + yo + outPad) * W1 + xo0 + outPad) * 4 + c4;
        if (outPad == 0) {
            nt_store(&lo_out[oidx], ac0);
            nt_store(&lo_out[oidx + 4], ac1);
        } else {
            lo_out[oidx] = ac0;
            lo_out[oidx + 4] = ac1;
        }
    }
}

// ---------------------------------------------------------------- launch

extern "C" void kernel_launch(void* const* d_in, const int* in_sizes, int n_in,
                              void* d_out, int out_size, void* d_ws, size_t ws_size,
                              hipStream_t stream) {
    const float* image   = (const float*)d_in[0];
    const float* lo0filt = (const float*)d_in[1];
    const float* hi0filt = (const float*)d_in[2];
    const float* lofilt  = (const float*)d_in[3];
    const float* bfilts  = (const float*)d_in[4];
    float* out = (float*)d_out;
    float* ws  = (float*)d_ws;

    const int N = 8, C = 16;
    size_t sz[5];
    const int Ws[5] = {256, 128, 64, 32, 16};
    for (int s = 0; s < 5; ++s) sz[s] = (size_t)N * Ws[s] * Ws[s] * C;

    // Workspace: P0 = image pad4 (264^2); L0..L3 = lo0..lo3 pad8.
    float* P0 = ws;
    float* L0 = P0 + (size_t)N * 264 * 264 * C;
    float* L1 = L0 + (size_t)N * 272 * 272 * C;
    float* L2 = L1 + (size_t)N * 144 * 144 * C;
    float* L3 = L2 + (size_t)N * 80 * 80 * C;

    // Output layout (reversed pyramid, flat):
    // [ lo_final | s=3 b=3..0 | s=2 b=3..0 | s=1 b=3..0 | s=0 b=3..0 | hi0 ]
    float* out_lofinal = out;
    size_t o = sz[4];
    float* band_ptr[4][4];
    for (int s = 3; s >= 0; --s)
        for (int b = 3; b >= 0; --b) { band_ptr[s][b] = out + o; o += sz[s]; }
    float* out_hi0 = out + o;

    // 1. zero pad borders of L0..L3
    zero_pads_all<<<2048, 256, 0, stream>>>(
        (float4*)L0, (float4*)L1, (float4*)L2, (float4*)L3);
    // 2. image -> P0 (pad 4)
    pad_copy_img<<<8 * 1089, 256, 0, stream>>>(
        (const float4*)image, (float4*)P0);
    // 3. hi0 (nt) + lo0 (cached), 4px x 2row
    dual_rows<<<8 * 128, 256, 0, stream>>>(
        (const float4*)P0, (float4*)out_hi0, (float4*)L0, hi0filt, lo0filt);
    // 4. lo1 = down(lo0)
    down17<8><<<8 * 128, 256, 0, stream>>>(
        (const float4*)L0, (float4*)L1, lofilt);
    // 5. bands s=0, 2px x 2row
    bands_rows<8><<<8 * 256, 256, 0, stream>>>(
        (const float4*)L0, (float4*)band_ptr[0][0], (float4*)band_ptr[0][1],
        (float4*)band_ptr[0][2], (float4*)band_ptr[0][3], bfilts);
    // 6. lo2 = down(lo1)
    down17<7><<<8 * 32, 256, 0, stream>>>(
        (const float4*)L1, (float4*)L2, lofilt);
    // 7. bands s=1
    bands_rows<7><<<8 * 64, 256, 0, stream>>>(
        (const float4*)L1, (float4*)band_ptr[1][0], (float4*)band_ptr[1][1],
        (float4*)band_ptr[1][2], (float4*)band_ptr[1][3], bfilts);
    // 8..9. scales 2..3 fused (bands + down)
    scale_fused2<6><<<8 * (32 + 8), 256, 0, stream>>>(
        (const float4*)L2, (float4*)band_ptr[2][0], (float4*)band_ptr[2][1],
        (float4*)band_ptr[2][2], (float4*)band_ptr[2][3], (float4*)L3,
        bfilts, lofilt, 8);
    scale_fused2<5><<<8 * (8 + 2), 256, 0, stream>>>(
        (const float4*)L3, (float4*)band_ptr[3][0], (float4*)band_ptr[3][1],
        (float4*)band_ptr[3][2], (float4*)band_ptr[3][3], (float4*)out_lofinal,
        bfilts, lofilt, 0);
}